// Round 11
// baseline (69.774 us; speedup 1.0000x reference)
//
#include <hip/hip_runtime.h>
#include <stdint.h>
#include <stddef.h>

typedef __bf16 bf16;
typedef __attribute__((ext_vector_type(8))) __bf16 bf16x8;
typedef __attribute__((ext_vector_type(4))) __bf16 bf16x4;
typedef __attribute__((ext_vector_type(4))) short short4_t;
typedef __attribute__((ext_vector_type(4))) float  f32x4;

// ---------------- geometry ----------------
// B = 262144. node: (B,19,4) f32, edge: (B,36,4) f32.
// compact first-4 nonzero rows of each -> x[32]; L1 32->256 relu; L2 256->128 relu;
// L3 128->34; log_softmax. Output (B,34) f32.
//
// L2/L3 use mfma 16x16x16 so each layer's B-operand is the lane's OWN packed
// output of the previous layer (D gives lane 4 consecutive features = exactly
// the 16x16x16 K-granularity k0=4*(l>>4)). No inter-layer LDS stage at all.
//
// Weight image in d_ws:
//   W1 @0:    16 frags x 1024B (16x16x32: lane16B = W1[k0..k0+8)[n], n=c*16+(l&15), k0=8*(l>>4))
//   W2 @16K: 128 frags x 512B (16x16x16: frag(nt2,c)=nt2*16+c; lane8B = W2[k0..k0+4)[n],
//            n=nt2*16+(l&15), k0=c*16+4*(l>>4))
//   W3 @80K:  24 frags x 512B (frag(nt3,c2)=nt3*8+c2, N padded 34->48 with zeros)
//   biases @92K: f32 b1[256] b2[128] b3[48] = 1728B
#define W1OFF  0
#define W2OFF  (16*1024)
#define W3OFF  (80*1024)
#define BOFF   (92*1024)
#define IMGSZ  (92*1024 + 1728)
#define NCHUNK (IMGSZ/16)      // 5996 16B chunks
#define PERW   2048            // per-wave: x tile double-buffer 2 x 1KB (no stage!)
#define LDSSZ  (IMGSZ + 8*PERW)   // 110272 B -> 1 block/CU, 8 waves

// swizzle for [16 rows][64B] bf16 tiles: XOR 16B-chunk index with (row>>1)&3
#define SWZ(s) ((((s)>>1)&3)<<4)

// 16x16x16 bf16 MFMA. NOTE: __has_builtin(__builtin_amdgcn_*) is FALSE in the
// HOST pass (R10 failure); host never codegens the __global__ body, so give it
// a dummy and dispatch builtin names only in the device pass.
#if !defined(__HIP_DEVICE_COMPILE__)
static __device__ __forceinline__ f32x4 mfma16(bf16x4 a, bf16x4 b, f32x4 c) {
  (void)a; (void)b; return c;   // host stub, never executed
}
#elif __has_builtin(__builtin_amdgcn_mfma_f32_16x16x16_bf16)
static __device__ __forceinline__ f32x4 mfma16(bf16x4 a, bf16x4 b, f32x4 c) {
  return __builtin_amdgcn_mfma_f32_16x16x16_bf16(a, b, c, 0, 0, 0);
}
#elif __has_builtin(__builtin_amdgcn_mfma_f32_16x16x16bf16_1k)
static __device__ __forceinline__ f32x4 mfma16(bf16x4 a, bf16x4 b, f32x4 c) {
  return __builtin_amdgcn_mfma_f32_16x16x16bf16_1k(
      __builtin_bit_cast(short4_t, a), __builtin_bit_cast(short4_t, b), c, 0, 0, 0);
}
#else
#error "no 16x16x16 bf16 mfma builtin on this toolchain (device pass)"
#endif

__global__ void prep_kernel(const float* __restrict__ W1, const float* __restrict__ b1,
                            const float* __restrict__ W2, const float* __restrict__ b2,
                            const float* __restrict__ W3, const float* __restrict__ b3,
                            char* __restrict__ img)
{
  int tid = blockIdx.x * 256 + threadIdx.x;
  if (tid < 1024) {                          // W1: 16 frags, 16x16x32 layout
    int fid = tid >> 6, l = tid & 63;
    int n = fid * 16 + (l & 15), k0 = 8 * (l >> 4);
    bf16x8 v;
    #pragma unroll
    for (int j = 0; j < 8; ++j) v[j] = (bf16)W1[(size_t)(k0 + j) * 256 + n];
    *(bf16x8*)(img + (size_t)tid * 16) = v;
  } else if (tid < 1024 + 8192) {            // W2: 128 frags, 16x16x16 layout
    int e = tid - 1024, frag = e >> 6, l = e & 63;
    int nt2 = frag >> 4, c = frag & 15;
    int n = nt2 * 16 + (l & 15), k0 = c * 16 + 4 * (l >> 4);
    bf16x4 v;
    #pragma unroll
    for (int j = 0; j < 4; ++j) v[j] = (bf16)W2[(size_t)(k0 + j) * 128 + n];
    *(bf16x4*)(img + W2OFF + (size_t)e * 8) = v;
  } else if (tid < 1024 + 8192 + 1536) {     // W3: 24 frags, 16x16x16 layout
    int e = tid - 9216, frag = e >> 6, l = e & 63;
    int nt3 = frag >> 3, c2 = frag & 7;
    int n = nt3 * 16 + (l & 15), k0 = c2 * 16 + 4 * (l >> 4);
    bf16x4 v;
    #pragma unroll
    for (int j = 0; j < 4; ++j)
      v[j] = (n < 34) ? (bf16)W3[(size_t)(k0 + j) * 34 + n] : (bf16)0.f;
    *(bf16x4*)(img + W3OFF + (size_t)e * 8) = v;
  } else if (tid < 1024 + 8192 + 1536 + 432) { // biases, flat f32
    int i = tid - 10752;
    float v;
    if (i < 256)      v = b1[i];
    else if (i < 384) v = b2[i - 256];
    else              { int j = i - 384; v = (j < 34) ? b3[j] : 0.f; }
    ((float*)(img + BOFF))[i] = v;
  }
}

// (512,2): the proven non-spilling shell (R1: 108 VGPR; all others spill).
__global__ __launch_bounds__(512, 2) void mlp_kernel(
    const float* __restrict__ node, const float* __restrict__ edge,
    const char* __restrict__ img, float* __restrict__ out)
{
  __shared__ __align__(16) char sm[LDSSZ];
  const int tid  = threadIdx.x;
  const int lane = tid & 63;
  const int w    = tid >> 6;                 // 0..7
  const int blk  = blockIdx.x;

  // stage weight image to LDS (coalesced 16B copies), one barrier total
  for (int c = tid; c < NCHUNK; c += 512)
    *(f32x4*)(sm + (size_t)c * 16) = *(const f32x4*)(img + (size_t)c * 16);
  __syncthreads();

  char* const xb0 = sm + IMGSZ + w * PERW;   // x tile buf A (1KB)
  char* const xb1 = xb0 + 1024;              // x tile buf B
  const float* const b1p = (const float*)(sm + BOFF);
  const float* const b2p = b1p + 256;
  const float* const b3p = b1p + 384;

  const int g   = lane >> 4;   // mfma 16-lane group
  const int m16 = lane & 15;   // sample col / weight row
  const int cl  = lane & 3;    // compaction lane within sample
  const int sl  = lane >> 2;   // compaction sample-in-tile (0..15)

  const float4* const np = (const float4*)node;   // 19 float4 per sample
  const float4* const ep = (const float4*)edge;   // 36 float4 per sample
  const f32x4 zf = {0.f, 0.f, 0.f, 0.f};

  float4 nf[5], ef[9];

  // wave-skewed pass order: breaks the all-waves-same-phase convoy on LDS/HBM.
  auto sample_of = [&](int p) { return blk * 1024 + (((p + w) & 7) * 128) + w * 16; };

  auto issue_loads = [&](int sbase) {
    const int s = sbase + sl;
    #pragma unroll
    for (int i = 0; i < 5; ++i) {
      const int r = cl + 4 * i;
      nf[i] = (r < 19) ? np[(size_t)s * 19 + r] : make_float4(0.f, 0.f, 0.f, 0.f);
    }
    #pragma unroll
    for (int i = 0; i < 9; ++i)
      ef[i] = ep[(size_t)s * 36 + cl + 4 * i];
  };

  auto compact = [&](char* dst) {
    uint32_t nm = 0; unsigned long long em = 0;
    #pragma unroll
    for (int i = 0; i < 5; ++i) {
      const int r = cl + 4 * i;
      if (r < 19 && (nf[i].x != 0.f || nf[i].y != 0.f || nf[i].z != 0.f || nf[i].w != 0.f))
        nm |= (1u << r);
    }
    #pragma unroll
    for (int i = 0; i < 9; ++i) {
      const int r = cl + 4 * i;
      if (ef[i].x != 0.f || ef[i].y != 0.f || ef[i].z != 0.f || ef[i].w != 0.f)
        em |= (1ull << r);
    }
    nm |= __shfl_xor(nm, 1); nm |= __shfl_xor(nm, 2);
    em |= __shfl_xor(em, 1); em |= __shfl_xor(em, 2);
    // zero-init my two 8B slots (8 slots covered by 4 lanes); wave-lockstep
    // guarantees zeros land before the data writes below.
    bf16x4 zb; zb[0] = (bf16)0.f; zb[1] = (bf16)0.f; zb[2] = (bf16)0.f; zb[3] = (bf16)0.f;
    *(bf16x4*)(dst + sl * 64 + ((8 * cl)      ^ SWZ(sl))) = zb;
    *(bf16x4*)(dst + sl * 64 + ((8 * cl + 32) ^ SWZ(sl))) = zb;
    #pragma unroll
    for (int i = 0; i < 5; ++i) {
      const int r = cl + 4 * i;
      if (r < 19 && ((nm >> r) & 1u)) {
        const int slot = __popc(nm & ((1u << r) - 1u));
        if (slot < 4) {
          bf16x4 pk; pk[0] = (bf16)nf[i].x; pk[1] = (bf16)nf[i].y; pk[2] = (bf16)nf[i].z; pk[3] = (bf16)nf[i].w;
          *(bf16x4*)(dst + sl * 64 + ((8 * slot) ^ SWZ(sl))) = pk;
        }
      }
    }
    #pragma unroll
    for (int i = 0; i < 9; ++i) {
      const int r = cl + 4 * i;
      if ((em >> r) & 1ull) {
        const int slot = __popcll(em & ((1ull << r) - 1ull));
        if (slot < 4) {
          bf16x4 pk; pk[0] = (bf16)ef[i].x; pk[1] = (bf16)ef[i].y; pk[2] = (bf16)ef[i].z; pk[3] = (bf16)ef[i].w;
          *(bf16x4*)(dst + sl * 64 + ((32 + 8 * slot) ^ SWZ(sl))) = pk;
        }
      }
    }
  };

  // prologue: pass 0 data
  issue_loads(sample_of(0));
  compact(xb0);

  #pragma unroll 1
  for (int p = 0; p < 8; ++p) {
    char* const xb = (p & 1) ? xb1 : xb0;
    char* const xn = (p & 1) ? xb0 : xb1;
    const int S = sample_of(p);
    const bool pf = (p < 7);

    if (pf) issue_loads(sample_of(p + 1));   // prefetch next pass
    asm volatile("" ::: "memory");           // keep loads issued before compute

    // x B-fragment (16x16x32): lane holds x[s=m16][8g .. 8g+8)
    bf16x8 xf = *(const bf16x8*)(xb + m16 * 64 + ((16 * g) ^ SWZ(m16)));

    // ---- L1 (32->256, 16x16x32) fused into L2 (256->128, 16x16x16) ----
    // d lane(g,m16) = h1[f=16c+4g+r][m16]; packed it IS the 16x16x16
    // B-fragment for K-chunk c. No LDS stage, no cross-lane.
    f32x4 acc2[8];
    #pragma unroll
    for (int i = 0; i < 8; ++i) acc2[i] = zf;

    #pragma unroll 2
    for (int c = 0; c < 16; ++c) {
      bf16x8 wf1 = *(const bf16x8*)(sm + W1OFF + c * 1024 + lane * 16);
      f32x4 d = __builtin_amdgcn_mfma_f32_16x16x32_bf16(wf1, xf, zf, 0, 0, 0);
      f32x4 b = *(const f32x4*)(b1p + c * 16 + 4 * g);
      bf16x4 h1p;
      #pragma unroll
      for (int r = 0; r < 4; ++r) h1p[r] = (bf16)fmaxf(d[r] + b[r], 0.f);
      #pragma unroll
      for (int nt2 = 0; nt2 < 8; ++nt2) {
        bf16x4 w2f = *(const bf16x4*)(sm + W2OFF + (size_t)((nt2 * 16 + c) * 512) + lane * 8);
        acc2[nt2] = mfma16(w2f, h1p, acc2[nt2]);
      }
    }

    // ---- L2 out -> L3 (128->48 padded, 16x16x16), same own-lane identity ----
    f32x4 acc3[3];
    #pragma unroll
    for (int i = 0; i < 3; ++i) acc3[i] = zf;

    #pragma unroll
    for (int c2 = 0; c2 < 8; ++c2) {
      f32x4 b = *(const f32x4*)(b2p + c2 * 16 + 4 * g);
      bf16x4 h2p;
      #pragma unroll
      for (int r = 0; r < 4; ++r) h2p[r] = (bf16)fmaxf(acc2[c2][r] + b[r], 0.f);
      #pragma unroll
      for (int nt3 = 0; nt3 < 3; ++nt3) {
        bf16x4 w3f = *(const bf16x4*)(sm + W3OFF + (size_t)((nt3 * 8 + c2) * 512) + lane * 8);
        acc3[nt3] = mfma16(w3f, h2p, acc3[nt3]);
      }
    }

    // ---- log_softmax over 34 classes (features spread over 4 lane-groups) ----
    float z[12];
    #pragma unroll
    for (int nt3 = 0; nt3 < 3; ++nt3) {
      f32x4 b = *(const f32x4*)(b3p + nt3 * 16 + 4 * g);
      #pragma unroll
      for (int r = 0; r < 4; ++r) {
        const int f = nt3 * 16 + 4 * g + r;
        z[nt3 * 4 + r] = (f < 34) ? (acc3[nt3][r] + b[r]) : -1e30f;
      }
    }
    float mx = z[0];
    #pragma unroll
    for (int i = 1; i < 12; ++i) mx = fmaxf(mx, z[i]);
    mx = fmaxf(mx, __shfl_xor(mx, 16));
    mx = fmaxf(mx, __shfl_xor(mx, 32));
    float sum = 0.f;
    #pragma unroll
    for (int i = 0; i < 12; ++i) sum += __expf(z[i] - mx);
    sum += __shfl_xor(sum, 16);
    sum += __shfl_xor(sum, 32);
    const float lse = mx + __logf(sum);

    float* orow = out + (size_t)(S + m16) * 34;
    *(float2*)(orow +  0 + 4 * g) = make_float2(z[0] - lse, z[1] - lse);
    *(float2*)(orow +  2 + 4 * g) = make_float2(z[2] - lse, z[3] - lse);
    *(float2*)(orow + 16 + 4 * g) = make_float2(z[4] - lse, z[5] - lse);
    *(float2*)(orow + 18 + 4 * g) = make_float2(z[6] - lse, z[7] - lse);
    if (g == 0)
      *(float2*)(orow + 32) = make_float2(z[8] - lse, z[9] - lse);

    if (pf) compact(xn);                     // build next pass's x tile
  }
}

extern "C" void kernel_launch(void* const* d_in, const int* in_sizes, int n_in,
                              void* d_out, int out_size, void* d_ws, size_t ws_size,
                              hipStream_t stream)
{
  const float* node = (const float*)d_in[0];
  const float* edge = (const float*)d_in[1];
  const float* W1   = (const float*)d_in[2];
  const float* b1   = (const float*)d_in[3];
  const float* W2   = (const float*)d_in[4];
  const float* b2   = (const float*)d_in[5];
  const float* W3   = (const float*)d_in[6];
  const float* b3   = (const float*)d_in[7];
  char* img = (char*)d_ws;

  prep_kernel<<<44, 256, 0, stream>>>(W1, b1, W2, b2, W3, b3, img);
  mlp_kernel<<<256, 512, 0, stream>>>(node, edge, img, (float*)d_out);
}

// Round 12
// 66.234 us; speedup vs baseline: 1.0534x; 1.0534x over previous
//
#include <hip/hip_runtime.h>
#include <stdint.h>
#include <stddef.h>

typedef __bf16 bf16;
typedef __attribute__((ext_vector_type(8))) __bf16 bf16x8;
typedef __attribute__((ext_vector_type(4))) __bf16 bf16x4;
typedef __attribute__((ext_vector_type(4))) float  f32x4;
typedef __attribute__((ext_vector_type(16))) float f32x16;

// ---------------- geometry ----------------
// B = 262144. node: (B,19,4) f32, edge: (B,36,4) f32.
// compact first-4 nonzero rows of each -> x[32]; L1 32->256 relu; L2 256->128 relu;
// L3 128->34 (pad 64); log_softmax. Output (B,34) f32.
//
// All layers use mfma_f32_32x32x16_bf16 (M=32 samples/wave-pass): weight reads
// amortize over 2x the samples vs 16x16; bias folded into MFMA C-init via
// prep-built bias D-fragment images; inter-layer repack via 2KB swizzled stage.
//
// 32x32x16 layouts: A lane l = W[k0..k0+8)[n], n=l&31, k0=8*(l>>5) (per frag's
// k-base); B lane l = x[k0..k0+8)[col=l&31]; D col=lane&31,
// row=(reg&3)+8*(reg>>2)+4*(lane>>5).
//
// Weight image in d_ws:
//   W1 @0:   16 frags x 1KB, frag(c,t)=c*2+t: k = t*16+8*hi+j, n = c*32+(l&31)
//   W2 @16K: 64 frags x 1KB, frag(nt2,c,t)=(nt2*8+c)*2+t: k = c*32+t*16+8hi+j, n = nt2*32+..
//   W3 @80K: 16 frags x 1KB, frag(nt3,c2,t)=(nt3*4+c2)*2+t (N pad 34->64, zeros)
//   bias D-frag images @96K: L1 8 chunks, L2 4, L3 2; each chunk 128B = f32[hi][reg],
//     value = b[chunk*32 + (reg&3)+8*(reg>>2)+4*hi]  (L3 pad -> 0)
#define W1OFF  0
#define W2OFF  (16*1024)
#define W3OFF  (80*1024)
#define BIOFF  (96*1024)
#define BI2OFF (BIOFF + 1024)
#define BI3OFF (BIOFF + 1536)
#define IMGSZ  (96*1024 + 1792)
#define NCHUNK (IMGSZ/16)        // 6256
#define PERW   4096              // per-wave: x tile 2KB + stage 2KB
#define LDSSZ  (IMGSZ + 8*PERW)  // 132864 -> 1 block/CU, 8 waves

// x-tile swizzle (16B-chunk idx XOR (row>>1)&3), as all prior rounds
#define SWZ(s) ((((s)>>1)&3)<<4)

#define MFMA32(a,b,c) __builtin_amdgcn_mfma_f32_32x32x16_bf16((a),(b),(c),0,0,0)

__global__ void prep_kernel(const float* __restrict__ W1, const float* __restrict__ b1,
                            const float* __restrict__ W2, const float* __restrict__ b2,
                            const float* __restrict__ W3, const float* __restrict__ b3,
                            char* __restrict__ img)
{
  int tid = blockIdx.x * 256 + threadIdx.x;
  if (tid < 1024) {                               // W1: 16 frags
    int frag = tid >> 6, l = tid & 63;
    int c = frag >> 1, t = frag & 1, hi = l >> 5;
    int n = c * 32 + (l & 31), k0 = t * 16 + 8 * hi;
    bf16x8 v;
    #pragma unroll
    for (int j = 0; j < 8; ++j) v[j] = (bf16)W1[(size_t)(k0 + j) * 256 + n];
    *(bf16x8*)(img + (size_t)tid * 16) = v;
  } else if (tid < 5120) {                        // W2: 64 frags
    int e = tid - 1024, frag = e >> 6, l = e & 63;
    int nt2 = frag >> 4, c = (frag >> 1) & 7, t = frag & 1, hi = l >> 5;
    int n = nt2 * 32 + (l & 31), k0 = c * 32 + t * 16 + 8 * hi;
    bf16x8 v;
    #pragma unroll
    for (int j = 0; j < 8; ++j) v[j] = (bf16)W2[(size_t)(k0 + j) * 128 + n];
    *(bf16x8*)(img + W2OFF + (size_t)e * 16) = v;
  } else if (tid < 6144) {                        // W3: 16 frags (N pad 64)
    int e = tid - 5120, frag = e >> 6, l = e & 63;
    int nt3 = frag >> 3, c2 = (frag >> 1) & 3, t = frag & 1, hi = l >> 5;
    int n = nt3 * 32 + (l & 31), k0 = c2 * 32 + t * 16 + 8 * hi;
    bf16x8 v;
    #pragma unroll
    for (int j = 0; j < 8; ++j)
      v[j] = (n < 34) ? (bf16)W3[(size_t)(k0 + j) * 34 + n] : (bf16)0.f;
    *(bf16x8*)(img + W3OFF + (size_t)e * 16) = v;
  } else if (tid < 6144 + 448) {                  // bias D-frag images
    int e = tid - 6144;
    int le, chunk, idx; const float* bsrc; char* dst; int nb;
    if (e < 256)      { le = e;       bsrc = b1; dst = img + BIOFF;  nb = 34; chunk = le >> 5; }
    else if (e < 384) { le = e - 256; bsrc = b2; dst = img + BI2OFF; nb = 1000; chunk = le >> 5; }
    else              { le = e - 384; bsrc = b3; dst = img + BI3OFF; nb = 34; chunk = le >> 5; }
    idx = le & 31;
    int hi = idx >> 4, reg = idx & 15;
    int f = chunk * 32 + (reg & 3) + 8 * (reg >> 2) + 4 * hi;
    float v;
    if (e < 256)      v = b1[f];
    else if (e < 384) v = b2[f];
    else              v = (f < 34) ? b3[f] : 0.f;
    (void)bsrc; (void)nb;
    ((float*)dst)[le] = v;
  }
}

// (512,2): the proven non-spilling shell.
__global__ __launch_bounds__(512, 2) void mlp_kernel(
    const float* __restrict__ node, const float* __restrict__ edge,
    const char* __restrict__ img, float* __restrict__ out)
{
  __shared__ __align__(16) char sm[LDSSZ];
  const int tid  = threadIdx.x;
  const int lane = tid & 63;
  const int w    = tid >> 6;                 // 0..7
  const int blk  = blockIdx.x;

  // stage weight+bias image to LDS (coalesced 16B copies), one barrier total
  for (int c = tid; c < NCHUNK; c += 512)
    *(f32x4*)(sm + (size_t)c * 16) = *(const f32x4*)(img + (size_t)c * 16);
  __syncthreads();

  char* const xw  = sm + IMGSZ + w * PERW;   // x tile (2KB: 32 rows x 64B)
  char* const stg = xw + 2048;               // stage (2KB: 32 cols x 64B)

  const int col = lane & 31;                 // sample-in-tile / D col
  const int hi  = lane >> 5;
  const int swz = (col >> 1) & 3;            // stage swizzle
  const int cl  = lane & 3;                  // compaction lane within sample
  const int sl  = lane >> 2;                 // compaction sample (0..15)

  const float4* const np = (const float4*)node;   // 19 float4 per sample
  const float4* const ep = (const float4*)edge;   // 36 float4 per sample

  float4 nf[5], ef[9];

  auto issue_loads = [&](int sbase) {
    const int s = sbase + sl;
    #pragma unroll
    for (int i = 0; i < 5; ++i) {
      const int r = cl + 4 * i;
      nf[i] = (r < 19) ? np[(size_t)s * 19 + r] : make_float4(0.f, 0.f, 0.f, 0.f);
    }
    #pragma unroll
    for (int i = 0; i < 9; ++i)
      ef[i] = ep[(size_t)s * 36 + cl + 4 * i];
  };

  auto compact = [&](char* dst) {            // 16 samples -> rows sl of dst
    uint32_t nm = 0; unsigned long long em = 0;
    #pragma unroll
    for (int i = 0; i < 5; ++i) {
      const int r = cl + 4 * i;
      if (r < 19 && (nf[i].x != 0.f || nf[i].y != 0.f || nf[i].z != 0.f || nf[i].w != 0.f))
        nm |= (1u << r);
    }
    #pragma unroll
    for (int i = 0; i < 9; ++i) {
      const int r = cl + 4 * i;
      if (ef[i].x != 0.f || ef[i].y != 0.f || ef[i].z != 0.f || ef[i].w != 0.f)
        em |= (1ull << r);
    }
    nm |= __shfl_xor(nm, 1); nm |= __shfl_xor(nm, 2);
    em |= __shfl_xor(em, 1); em |= __shfl_xor(em, 2);
    bf16x4 zb; zb[0] = (bf16)0.f; zb[1] = (bf16)0.f; zb[2] = (bf16)0.f; zb[3] = (bf16)0.f;
    *(bf16x4*)(dst + sl * 64 + ((8 * cl)      ^ SWZ(sl))) = zb;
    *(bf16x4*)(dst + sl * 64 + ((8 * cl + 32) ^ SWZ(sl))) = zb;
    #pragma unroll
    for (int i = 0; i < 5; ++i) {
      const int r = cl + 4 * i;
      if (r < 19 && ((nm >> r) & 1u)) {
        const int slot = __popc(nm & ((1u << r) - 1u));
        if (slot < 4) {
          bf16x4 pk; pk[0] = (bf16)nf[i].x; pk[1] = (bf16)nf[i].y; pk[2] = (bf16)nf[i].z; pk[3] = (bf16)nf[i].w;
          *(bf16x4*)(dst + sl * 64 + ((8 * slot) ^ SWZ(sl))) = pk;
        }
      }
    }
    #pragma unroll
    for (int i = 0; i < 9; ++i) {
      const int r = cl + 4 * i;
      if ((em >> r) & 1ull) {
        const int slot = __popcll(em & ((1ull << r) - 1ull));
        if (slot < 4) {
          bf16x4 pk; pk[0] = (bf16)ef[i].x; pk[1] = (bf16)ef[i].y; pk[2] = (bf16)ef[i].z; pk[3] = (bf16)ef[i].w;
          *(bf16x4*)(dst + sl * 64 + ((32 + 8 * slot) ^ SWZ(sl))) = pk;
        }
      }
    }
  };

  auto ldbias = [&](const char* p) -> f32x16 {   // 128B chunk img -> f32x16 (by reg)
    const f32x4* q4 = (const f32x4*)(p + hi * 64);
    f32x4 q0 = q4[0], q1 = q4[1], q2 = q4[2], q3 = q4[3];
    f32x16 r;
    #pragma unroll
    for (int i = 0; i < 4; ++i) { r[i] = q0[i]; r[4+i] = q1[i]; r[8+i] = q2[i]; r[12+i] = q3[i]; }
    return r;
  };

  #pragma unroll 1
  for (int p = 0; p < 4; ++p) {
    const int S = blk * 1024 + p * 256 + w * 32;

    // ---- build 32-sample x tile (two 16-sample compacts) ----
    issue_loads(S);       compact(xw);
    issue_loads(S + 16);  compact(xw + 1024);

    // x B-frags: t-th frag = x[k=t*16+8hi .. +8)[col]; chunk idx 2t+hi, SWZ(col)
    bf16x8 xf0 = *(const bf16x8*)(xw + col * 64 + ((hi * 16)      ^ SWZ(col)));
    bf16x8 xf1 = *(const bf16x8*)(xw + col * 64 + ((32 + hi * 16) ^ SWZ(col)));

    // ---- L1 (32->256) fused into L2 (256->128), per 32-feature chunk ----
    f32x16 acc2[4];
    #pragma unroll
    for (int nt2 = 0; nt2 < 4; ++nt2) acc2[nt2] = ldbias(sm + BI2OFF + nt2 * 128);

    #pragma unroll 1
    for (int c = 0; c < 8; ++c) {
      __builtin_amdgcn_sched_barrier(0);
      f32x16 d = ldbias(sm + BIOFF + c * 128);      // bias folded into C
      bf16x8 w10 = *(const bf16x8*)(sm + W1OFF + (c * 2 + 0) * 1024 + lane * 16);
      bf16x8 w11 = *(const bf16x8*)(sm + W1OFF + (c * 2 + 1) * 1024 + lane * 16);
      d = MFMA32(w10, xf0, d);
      d = MFMA32(w11, xf1, d);
      // relu+pack -> stage: quad q = k_local 8q+4hi+0..3, chunk idx q ^ swz
      #pragma unroll
      for (int q = 0; q < 4; ++q) {
        bf16x4 pk;
        #pragma unroll
        for (int i = 0; i < 4; ++i) pk[i] = (bf16)fmaxf(d[4 * q + i], 0.f);
        *(bf16x4*)(stg + col * 64 + (((q ^ swz) << 4) + hi * 8)) = pk;
      }
      bf16x8 sf0 = *(const bf16x8*)(stg + col * 64 + (((0 + hi) ^ swz) << 4));
      bf16x8 sf1 = *(const bf16x8*)(stg + col * 64 + (((2 + hi) ^ swz) << 4));
      #pragma unroll
      for (int nt2 = 0; nt2 < 4; ++nt2) {
        bf16x8 a0 = *(const bf16x8*)(sm + W2OFF + ((nt2 * 8 + c) * 2 + 0) * 1024 + lane * 16);
        bf16x8 a1 = *(const bf16x8*)(sm + W2OFF + ((nt2 * 8 + c) * 2 + 1) * 1024 + lane * 16);
        acc2[nt2] = MFMA32(a0, sf0, acc2[nt2]);
        acc2[nt2] = MFMA32(a1, sf1, acc2[nt2]);
      }
    }

    // ---- L2 out -> L3 (128 -> 64 padded), K-chunk c2 = acc2[c2] ----
    f32x16 acc3[2];
    acc3[0] = ldbias(sm + BI3OFF + 0);
    acc3[1] = ldbias(sm + BI3OFF + 128);

    #pragma unroll   // full unroll: acc2[c2] must be statically indexed (no scratch)
    for (int c2 = 0; c2 < 4; ++c2) {
      #pragma unroll
      for (int q = 0; q < 4; ++q) {
        bf16x4 pk;
        #pragma unroll
        for (int i = 0; i < 4; ++i) pk[i] = (bf16)fmaxf(acc2[c2][4 * q + i], 0.f);
        *(bf16x4*)(stg + col * 64 + (((q ^ swz) << 4) + hi * 8)) = pk;
      }
      bf16x8 sf0 = *(const bf16x8*)(stg + col * 64 + (((0 + hi) ^ swz) << 4));
      bf16x8 sf1 = *(const bf16x8*)(stg + col * 64 + (((2 + hi) ^ swz) << 4));
      #pragma unroll
      for (int nt3 = 0; nt3 < 2; ++nt3) {
        bf16x8 a0 = *(const bf16x8*)(sm + W3OFF + ((nt3 * 4 + c2) * 2 + 0) * 1024 + lane * 16);
        bf16x8 a1 = *(const bf16x8*)(sm + W3OFF + ((nt3 * 4 + c2) * 2 + 1) * 1024 + lane * 16);
        acc3[nt3] = MFMA32(a0, sf0, acc3[nt3]);
        acc3[nt3] = MFMA32(a1, sf1, acc3[nt3]);
      }
    }

    // ---- log_softmax: lane holds classes 8q+4hi+0..3 (chunk0) of sample col;
    //      classes 32,33 live in hi==0 lanes' acc3[1][0..1]. Pads excluded. ----
    float mx = acc3[0][0];
    #pragma unroll
    for (int i = 1; i < 16; ++i) mx = fmaxf(mx, acc3[0][i]);
    if (hi == 0) { mx = fmaxf(mx, acc3[1][0]); mx = fmaxf(mx, acc3[1][1]); }
    mx = fmaxf(mx, __shfl_xor(mx, 32));
    float sum = 0.f;
    #pragma unroll
    for (int i = 0; i < 16; ++i) sum += __expf(acc3[0][i] - mx);
    if (hi == 0) sum += __expf(acc3[1][0] - mx) + __expf(acc3[1][1] - mx);
    sum += __shfl_xor(sum, 32);
    const float lse = mx + __logf(sum);

    float* orow = out + (size_t)(S + col) * 34;
    #pragma unroll
    for (int q = 0; q < 4; ++q) {
      *(float2*)(orow + 8 * q + 4 * hi)     = make_float2(acc3[0][4 * q]     - lse, acc3[0][4 * q + 1] - lse);
      *(float2*)(orow + 8 * q + 4 * hi + 2) = make_float2(acc3[0][4 * q + 2] - lse, acc3[0][4 * q + 3] - lse);
    }
    if (hi == 0)
      *(float2*)(orow + 32) = make_float2(acc3[1][0] - lse, acc3[1][1] - lse);
  }
}

extern "C" void kernel_launch(void* const* d_in, const int* in_sizes, int n_in,
                              void* d_out, int out_size, void* d_ws, size_t ws_size,
                              hipStream_t stream)
{
  const float* node = (const float*)d_in[0];
  const float* edge = (const float*)d_in[1];
  const float* W1   = (const float*)d_in[2];
  const float* b1   = (const float*)d_in[3];
  const float* W2   = (const float*)d_in[4];
  const float* b2   = (const float*)d_in[5];
  const float* W3   = (const float*)d_in[6];
  const float* b3   = (const float*)d_in[7];
  char* img = (char*)d_ws;

  prep_kernel<<<26, 256, 0, stream>>>(W1, b1, W2, b2, W3, b3, img);
  mlp_kernel<<<256, 512, 0, stream>>>(node, edge, img, (float*)d_out);
}